// Round 19
// baseline (87.560 us; speedup 1.0000x reference)
//
#include <hip/hip_runtime.h>

#define EPS 1e-5f

typedef _Float16 half4_t __attribute__((ext_vector_type(4)));
typedef _Float16 half8_t __attribute__((ext_vector_type(8)));
typedef float floatx4 __attribute__((ext_vector_type(4)));

__device__ __forceinline__ unsigned short f2hb(float f) {
  _Float16 h = (_Float16)f;
  return __builtin_bit_cast(unsigned short, h);
}
__device__ __forceinline__ float hb2f(unsigned short u) {
  return (float)__builtin_bit_cast(_Float16, u);
}
__device__ __forceinline__ unsigned int pack2(float a, float b) {
  return (unsigned int)f2hb(a) | ((unsigned int)f2hb(b) << 16);
}

// ws layout (bytes):
//   qkv_h (fp16 v rows): [512 b][8 g][32 c][64 h]   @ 0         (16,777,216)
//   qkT   (fp16): [512 b][8 g][64 h][32 c]          @ 16777216  (16,777,216)
//   Wh    (fp16): [512 o][256 k]                    @ 33554432  (262,144)
//   relTq (fp16): [128 t][16 c]                     @ 33816576  (4096)
//   relTk (fp16): [128 t][16 c]                     @ 33820672  (4096)
//   relV  (fp16): [32 c][128 t]                     @ 33824768  (8192)
//   bnsF  (f32) : [8 g][4]                          @ 33832960  (128)
//   bnoSc (f32) : [512]                             @ 33833088  (2048)
//   bnoSh (f32) : [512]                             @ 33835136  (2048)
//   bnqSc (f32) : [512]                             @ 33837184  (2048)
//   bnqSh (f32) : [512]                             @ 33839232  (2048)
#define WS_QKT 16777216
#define WS_WH 33554432
#define WS_RELTQ 33816576
#define WS_RELTK 33820672
#define WS_RELV 33824768
#define WS_BNSF 33832960
#define WS_BNOSC 33833088
#define WS_BNOSH 33835136
#define WS_BNQSC 33837184
#define WS_BNQSH 33839232

// ---------------------------------------------------------------------------
// Kernel 0: prep. blocks 0..7: W -> Wh fp16. block 8: rel tables + folded BN.
// ---------------------------------------------------------------------------
__global__ __launch_bounds__(256) void k_prep(const float* __restrict__ W,
                                              const float* __restrict__ bnq,
                                              const float* __restrict__ rel,
                                              const float* __restrict__ bns,
                                              const float* __restrict__ bno,
                                              char* __restrict__ ws) {
  const int bid = blockIdx.x, tid = threadIdx.x;
  if (bid < 8) {
    unsigned short* Wh = (unsigned short*)(ws + WS_WH);
    const int base = bid * 16384;
#pragma unroll
    for (int u = 0; u < 16; ++u) {
      const int i = base + u * 1024 + tid * 4;
      const float4 v = *reinterpret_cast<const float4*>(&W[i]);
      uint2 p;
      p.x = pack2(v.x, v.y);
      p.y = pack2(v.z, v.w);
      *reinterpret_cast<uint2*>(&Wh[i]) = p;
    }
  } else {
    unsigned short* relTq = (unsigned short*)(ws + WS_RELTQ);
    unsigned short* relTk = (unsigned short*)(ws + WS_RELTK);
    unsigned short* relV = (unsigned short*)(ws + WS_RELV);
    float* bnsF = (float*)(ws + WS_BNSF);
    float* bnoSc = (float*)(ws + WS_BNOSC);
    float* bnoSh = (float*)(ws + WS_BNOSH);
    float* bnqSc = (float*)(ws + WS_BNQSC);
    float* bnqSh = (float*)(ws + WS_BNQSH);
    for (int idx = tid; idx < 2048; idx += 256) {
      const int t = idx >> 4, c = idx & 15;
      relTq[idx] = (t < 127) ? f2hb(rel[c * 127 + t]) : (unsigned short)0;
      relTk[idx] = (t < 127) ? f2hb(rel[(16 + c) * 127 + t]) : (unsigned short)0;
    }
    for (int idx = tid; idx < 4096; idx += 256) {
      const int c = idx >> 7, t = idx & 127;
      relV[idx] = (t < 127) ? f2hb(rel[(32 + c) * 127 + t]) : (unsigned short)0;
    }
    if (tid < 8) {
      const int g = tid;
      const float scA = bns[g] / sqrtf(bns[72 + g] + EPS);
      const float scB = bns[8 + g] / sqrtf(bns[72 + 8 + g] + EPS);
      const float scC = bns[16 + g] / sqrtf(bns[72 + 16 + g] + EPS);
      const float shv = (bns[24 + g] - bns[48 + g] * scA) +
                        (bns[24 + 8 + g] - bns[48 + 8 + g] * scB) +
                        (bns[24 + 16 + g] - bns[48 + 16 + g] * scC);
      bnsF[g * 4 + 0] = scA;
      bnsF[g * 4 + 1] = scB;
      bnsF[g * 4 + 2] = scC;
      bnsF[g * 4 + 3] = shv;
    }
    for (int idx = tid; idx < 512; idx += 256) {
      const float sc = bno[idx] / sqrtf(bno[1536 + idx] + EPS);
      bnoSc[idx] = sc;
      bnoSh[idx] = bno[512 + idx] - bno[1024 + idx] * sc;
      const float qc = bnq[idx] / sqrtf(bnq[1536 + idx] + EPS);
      bnqSc[idx] = qc;
      bnqSh[idx] = bnq[512 + idx] - bnq[1024 + idx] * qc;
    }
  }
}

// ---------------------------------------------------------------------------
// Kernel 1: fused qkv = BN(Wh @ x-slice). (unchanged from r16)
// ---------------------------------------------------------------------------
__global__ __launch_bounds__(512, 4) void k_qkv(const float* __restrict__ x,
                                                char* __restrict__ ws) {
  const unsigned short* Wh = (const unsigned short*)(ws + WS_WH);
  const float* bnqSc = (const float*)(ws + WS_BNQSC);
  const float* bnqSh = (const float*)(ws + WS_BNQSH);
  unsigned short* qkv_h = (unsigned short*)ws;
  unsigned short* qkT = (unsigned short*)(ws + WS_QKT);
  __shared__ __align__(16) char arena[36864];
  unsigned short* xT = (unsigned short*)arena;    // [64 n][280]  35840B (ph A-B)
  unsigned short* qk_t = (unsigned short*)arena;  // [8 g][64 h][36] 36864B (ph C)

  const int tid = threadIdx.x;
  const int lane = tid & 63;
  const int w = tid >> 6;  // wave index == group g
  const int l15 = lane & 15, kg = lane >> 4;
  const size_t b = blockIdx.x;
  const int n0g = (int)b * 64;

  // ---- phase A: stage x slice -> xT fp16 [n][k], stride 280 ----
  {
    const int k = tid >> 1;         // 0..255
    const int nb = (tid & 1) * 32;  // 0 / 32
    const float* src = x + (size_t)k * 32768 + n0g + nb;
    unsigned short hv[32];
#pragma unroll
    for (int u = 0; u < 8; ++u) {
      const float4 v4 = *reinterpret_cast<const float4*>(src + u * 4);
      hv[u * 4 + 0] = f2hb(v4.x);
      hv[u * 4 + 1] = f2hb(v4.y);
      hv[u * 4 + 2] = f2hb(v4.z);
      hv[u * 4 + 3] = f2hb(v4.w);
    }
#pragma unroll
    for (int e = 0; e < 32; ++e) xT[(nb + e) * 280 + k] = hv[e];
  }
  __syncthreads();

  // ---- phase B: GEMM. wave w: o rows [w*64, w*64+64) x 64 n ----
  floatx4 acc[4][4] = {};
#pragma unroll
  for (int kk = 0; kk < 8; ++kk) {
    half8_t af[4], bf[4];
#pragma unroll
    for (int fm = 0; fm < 4; ++fm)
      af[fm] = *reinterpret_cast<const half8_t*>(Wh + (size_t)(w * 64 + fm * 16 + l15) * 256 +
                                                 kk * 32 + kg * 8);
#pragma unroll
    for (int fn = 0; fn < 4; ++fn)
      bf[fn] = *reinterpret_cast<const half8_t*>(xT + (fn * 16 + l15) * 280 + kk * 32 + kg * 8);
#pragma unroll
    for (int fm = 0; fm < 4; ++fm)
#pragma unroll
      for (int fn = 0; fn < 4; ++fn)
        acc[fm][fn] = __builtin_amdgcn_mfma_f32_16x16x32_f16(af[fm], bf[fn], acc[fm][fn], 0, 0, 0);
  }
  __syncthreads();  // xT dead; qk_t overlay live

  // ---- phase C: BN epilogue. q/k -> qk_t[h][c] (b64); v -> global direct ----
  const int o0 = w * 64;
#pragma unroll
  for (int fm = 0; fm < 4; ++fm) {
    const float4 sc4 = *reinterpret_cast<const float4*>(&bnqSc[o0 + fm * 16 + kg * 4]);
    const float4 sh4 = *reinterpret_cast<const float4*>(&bnqSh[o0 + fm * 16 + kg * 4]);
#pragma unroll
    for (int fn = 0; fn < 4; ++fn) {
      const int h = fn * 16 + l15;
      const float v0 = fmaf(acc[fm][fn][0], sc4.x, sh4.x);
      const float v1 = fmaf(acc[fm][fn][1], sc4.y, sh4.y);
      const float v2 = fmaf(acc[fm][fn][2], sc4.z, sh4.z);
      const float v3 = fmaf(acc[fm][fn][3], sc4.w, sh4.w);
      if (fm < 2) {
        uint2 p;
        p.x = pack2(v0, v1);
        p.y = pack2(v2, v3);
        *reinterpret_cast<uint2*>(&qk_t[w * 2304 + h * 36 + fm * 16 + kg * 4]) = p;
      } else {
        const int cb = (fm - 2) * 16 + kg * 4;
        unsigned short* dst = &qkv_h[((b * 8 + w) * 32 + cb) * 64 + h];
        dst[0] = f2hb(v0);
        dst[64] = f2hb(v1);
        dst[128] = f2hb(v2);
        dst[192] = f2hb(v3);
      }
    }
  }
  __syncthreads();
  // ---- cooperative coalesced qkT stores: 8 tiles x 4KB ----
#pragma unroll
  for (int it = 0; it < 4; ++it) {
    const int idx = it * 512 + tid;
    const int g2 = idx >> 8, e = idx & 255;
    const int h = e >> 2, c0 = (e & 3) * 8;
    const unsigned short* srcp = &qk_t[g2 * 2304 + h * 36 + c0];
    const uint2 a = *reinterpret_cast<const uint2*>(srcp);
    const uint2 b2 = *reinterpret_cast<const uint2*>(srcp + 4);
    uint4 wv;
    wv.x = a.x;
    wv.y = a.y;
    wv.z = b2.x;
    wv.w = b2.y;
    *reinterpret_cast<uint4*>(&qkT[((b * 8 + g2) * 64 + h) * 32 + c0]) = wv;
  }
}

// ---------------------------------------------------------------------------
// Kernel 2: attention, 2 (b,g) pairs per block (grid 2048), all 4 global
// loads (qkT x2, V x2) issued at entry into registers -> pair-1's latency
// hides under pair-0's compute. qkL dedicated (no overlay hazard).
// Arena 37376 B -> 4 blocks/CU.
// ---------------------------------------------------------------------------
#define QKS 36   // qkL row stride (halves)
#define PBS 72   // Pb / Vb row stride (halves)
#define PPS 136  // Pp row stride (halves)

__global__ __launch_bounds__(256, 4) void k_attn(const char* __restrict__ ws,
                                                 float* __restrict__ out) {
  const unsigned short* qkv_h = (const unsigned short*)ws;
  const unsigned short* qkTg = (const unsigned short*)(ws + WS_QKT);
  const unsigned short* relTq = (const unsigned short*)(ws + WS_RELTQ);
  const unsigned short* relTk = (const unsigned short*)(ws + WS_RELTK);
  const unsigned short* relV = (const unsigned short*)(ws + WS_RELV);
  const float* bnsF = (const float*)(ws + WS_BNSF);
  const float* bnoSc = (const float*)(ws + WS_BNOSC);
  const float* bnoSh = (const float*)(ws + WS_BNOSH);

  __shared__ __align__(16) char arena[37376];
  unsigned short* qkL = (unsigned short*)arena;            // [64][36]   4608 (dedicated)
  unsigned short* M1T = (unsigned short*)(arena + 4608);   // [128][64] 16384 (ph2-3a)
  unsigned short* M2T = (unsigned short*)(arena + 20992);  // [128][64] 16384
  unsigned short* Pb = (unsigned short*)(arena + 4608);    // [64][72]   9216 (ph3b-5)
  unsigned short* Pp = (unsigned short*)(arena + 13824);   // [64][136] 17408
  unsigned short* Vb = (unsigned short*)(arena + 31232);   // [32][72]   4608
  float* rowsumL = (float*)(arena + 35840);                // [64]        256

  const int tid = threadIdx.x;
  const int lane = tid & 63;
  const int wid = tid >> 6;
  const int l15 = lane & 15, kg = lane >> 4;
  const size_t idx0 = (size_t)blockIdx.x * 2;

  // ---- entry: issue ALL four global loads (both pairs) ----
  const uint4 qvA = *reinterpret_cast<const uint4*>(&qkTg[idx0 * 2048 + tid * 8]);
  const uint4 qvB = *reinterpret_cast<const uint4*>(&qkTg[(idx0 + 1) * 2048 + tid * 8]);
  const uint4 vlA = *reinterpret_cast<const uint4*>(
      &qkv_h[(idx0 * 32 + (tid >> 3)) * 64 + (tid & 7) * 8]);
  const uint4 vlB = *reinterpret_cast<const uint4*>(
      &qkv_h[((idx0 + 1) * 32 + (tid >> 3)) * 64 + (tid & 7) * 8]);

#pragma unroll
  for (int p = 0; p < 2; ++p) {
    const size_t idx = idx0 + p;
    const int b = (int)(idx >> 3), g = (int)(idx & 7);
    const uint4 qv = (p == 0) ? qvA : qvB;
    const uint4 vld = (p == 0) ? vlA : vlB;

    // ---- phase 1: write qkL from prefetched regs ----
    {
      const int i = tid >> 2, c0 = (tid & 3) * 8;
      uint2 lo, hi;
      lo.x = qv.x;
      lo.y = qv.y;
      hi.x = qv.z;
      hi.y = qv.w;
      *reinterpret_cast<uint2*>(&qkL[i * QKS + c0]) = lo;
      *reinterpret_cast<uint2*>(&qkL[i * QKS + c0 + 4]) = hi;
    }
    __syncthreads();

    // ---- phase 1b: preload q/k fragments to registers ----
    const half4_t aq = *reinterpret_cast<const half4_t*>(&qkL[(wid * 16 + l15) * QKS + kg * 4]);
    const half4_t ak =
        *reinterpret_cast<const half4_t*>(&qkL[(wid * 16 + l15) * QKS + 16 + kg * 4]);
    half4_t bqr[4];
#pragma unroll
    for (int nt = 0; nt < 4; ++nt)
      bqr[nt] = *reinterpret_cast<const half4_t*>(&qkL[(nt * 16 + l15) * QKS + 16 + kg * 4]);
    __syncthreads();

    // ---- phase 2: K=16 MFMAs: qk (regs), M1T/M2T (swizzled stride-64) ----
    floatx4 qkreg[4];
    {
      half4_t brq[8], brk[8];
#pragma unroll
      for (int nt = 0; nt < 8; ++nt) {
        brq[nt] = *reinterpret_cast<const half4_t*>(&relTq[(nt * 16 + l15) * 16 + kg * 4]);
        brk[nt] = *reinterpret_cast<const half4_t*>(&relTk[(nt * 16 + l15) * 16 + kg * 4]);
      }
      __builtin_amdgcn_s_setprio(1);
#pragma unroll
      for (int nt = 0; nt < 4; ++nt) {
        const floatx4 z = {};
        qkreg[nt] = __builtin_amdgcn_mfma_f32_16x16x16f16(aq, bqr[nt], z, 0, 0, 0);
      }
      const int mcol = wid * 16 + kg * 4;
#pragma unroll
      for (int nt = 0; nt < 8; ++nt) {
        const floatx4 z = {};
        const floatx4 cr = __builtin_amdgcn_mfma_f32_16x16x16f16(aq, brq[nt], z, 0, 0, 0);
        const int row = nt * 16 + l15;
        uint2 pq;
        pq.x = pack2(cr[0], cr[1]);
        pq.y = pack2(cr[2], cr[3]);
        *reinterpret_cast<uint2*>(&M1T[row * 64 + (mcol ^ ((row & 7) << 3))]) = pq;
      }
#pragma unroll
      for (int nt = 0; nt < 8; ++nt) {
        const floatx4 z = {};
        const floatx4 cr = __builtin_amdgcn_mfma_f32_16x16x16f16(ak, brk[nt], z, 0, 0, 0);
        const int row = nt * 16 + l15;
        uint2 pq;
        pq.x = pack2(cr[0], cr[1]);
        pq.y = pack2(cr[2], cr[3]);
        *reinterpret_cast<uint2*>(&M2T[row * 64 + (mcol ^ ((row & 7) << 3))]) = pq;
      }
      __builtin_amdgcn_s_setprio(0);
    }
    __syncthreads();

    // ---- phase 3a: gather M1T/M2T (swizzled), assemble S in registers ----
    float sreg[4][4];
    {
      const float4 bf = *reinterpret_cast<const float4*>(&bnsF[g * 4]);
#pragma unroll
      for (int nt = 0; nt < 4; ++nt) {
        const int j = nt * 16 + l15;
#pragma unroll
        for (int r = 0; r < 4; ++r) {
          const int i = wid * 16 + kg * 4 + r;
          const int d = i - j + 63;  // 0..126
          const int d2 = 126 - d;
          const float qr = hb2f(M1T[d * 64 + (i ^ ((d & 7) << 3))]);
          const float kr = hb2f(M2T[d2 * 64 + (j ^ ((d2 & 7) << 3))]);
          sreg[nt][r] = fmaf(bf.x, qkreg[nt][r], fmaf(bf.y, qr, fmaf(bf.z, kr, bf.w)));
        }
      }
    }
    __syncthreads();  // M1T/M2T dead; Pb/Pp/Vb/rowsum overlay live

    // ---- phase 3b: in-register softmax; Pp zero (b64 segmented) + scatter ----
    float sm[4];
#pragma unroll
    for (int r = 0; r < 4; ++r) {
      float m = fmaxf(fmaxf(sreg[0][r], sreg[1][r]), fmaxf(sreg[2][r], sreg[3][r]));
      m = fmaxf(m, __shfl_xor(m, 1));
      m = fmaxf(m, __shfl_xor(m, 2));
      m = fmaxf(m, __shfl_xor(m, 4));
      m = fmaxf(m, __shfl_xor(m, 8));
      float s = 0.f;
#pragma unroll
      for (int nt = 0; nt < 4; ++nt) {
        sreg[nt][r] = __expf(sreg[nt][r] - m);
        s += sreg[nt][r];
      }
      s += __shfl_xor(s, 1);
      s += __shfl_xor(s, 2);
      s += __shfl_xor(s, 4);
      s += __shfl_xor(s, 8);
      sm[r] = s;
    }
#pragma unroll
    for (int r = 0; r < 4; ++r) {
      const int i = wid * 16 + kg * 4 + r;
      const int z0 = l15 * 4;
      if (z0 + 3 < i) {
        uint2 zz;
        zz.x = 0u;
        zz.y = 0u;
        *reinterpret_cast<uint2*>(&Pp[i * PPS + z0]) = zz;
      } else if (z0 >= i) {
        uint2 zz;
        zz.x = 0u;
        zz.y = 0u;
        *reinterpret_cast<uint2*>(&Pp[i * PPS + z0 + 64]) = zz;
      } else {
#pragma unroll
        for (int e = 0; e < 4; ++e) {
          const int z = z0 + e;
          Pp[i * PPS + (z < i ? z : z + 64)] = 0;
        }
      }
#pragma unroll
      for (int nt = 0; nt < 4; ++nt) {
        const int j = nt * 16 + l15;
        const unsigned short pv = f2hb(sreg[nt][r]);
        Pb[i * PBS + j] = pv;
        Pp[i * PPS + i + 63 - j] = pv;
      }
      if (l15 == 0) rowsumL[i] = sm[r];
    }
    {
      *reinterpret_cast<uint4*>(&Vb[(tid >> 3) * PBS + (tid & 7) * 8]) = vld;
    }
    __syncthreads();

    // ---- phase 5: swapped sv/sve MFMAs -> D[c][i]; direct global epilogue ----
    floatx4 sva[2] = {}, svea[2] = {};
    __builtin_amdgcn_s_setprio(1);
#pragma unroll
    for (int kk = 0; kk < 2; ++kk) {
      const half8_t pbf =
          *reinterpret_cast<const half8_t*>(&Pb[(wid * 16 + l15) * PBS + kk * 32 + kg * 8]);
#pragma unroll
      for (int cf = 0; cf < 2; ++cf) {
        const half8_t vb =
            *reinterpret_cast<const half8_t*>(&Vb[(cf * 16 + l15) * PBS + kk * 32 + kg * 8]);
        sva[cf] = __builtin_amdgcn_mfma_f32_16x16x32_f16(vb, pbf, sva[cf], 0, 0, 0);
      }
    }
#pragma unroll
    for (int kk = 0; kk < 4; ++kk) {
      const half8_t ppf =
          *reinterpret_cast<const half8_t*>(&Pp[(wid * 16 + l15) * PPS + kk * 32 + kg * 8]);
#pragma unroll
      for (int cf = 0; cf < 2; ++cf) {
        const half8_t rb =
            *reinterpret_cast<const half8_t*>(&relV[(cf * 16 + l15) * 128 + kk * 32 + kg * 8]);
        svea[cf] = __builtin_amdgcn_mfma_f32_16x16x32_f16(rb, ppf, svea[cf], 0, 0, 0);
      }
    }
    __builtin_amdgcn_s_setprio(0);
    {
      const int i = wid * 16 + l15;
      const float inv = 1.0f / rowsumL[i];
#pragma unroll
      for (int cf = 0; cf < 2; ++cf) {
#pragma unroll
        for (int reg = 0; reg < 4; ++reg) {
          const int c = cf * 16 + kg * 4 + reg;
          const int ch = ((g << 5) + c) * 2;
          const float2 scv = *reinterpret_cast<const float2*>(&bnoSc[ch]);
          const float2 shv = *reinterpret_cast<const float2*>(&bnoSh[ch]);
          out[(size_t)((g << 5) + c) * 32768 + (size_t)b * 64 + i] =
              fmaf(scv.x, sva[cf][reg] * inv, shv.x) + fmaf(scv.y, svea[cf][reg] * inv, shv.y);
        }
      }
    }
  }
}

extern "C" void kernel_launch(void* const* d_in, const int* in_sizes, int n_in,
                              void* d_out, int out_size, void* d_ws, size_t ws_size,
                              hipStream_t stream) {
  const float* x = (const float*)d_in[0];         // (1,256,16,32,64)
  const float* qkv_w = (const float*)d_in[1];     // (512,256)
  const float* relative = (const float*)d_in[2];  // (64,127)
  const float* bn_qkv = (const float*)d_in[3];    // (4,512)
  const float* bn_sim = (const float*)d_in[4];    // (4,24)
  const float* bn_out = (const float*)d_in[5];    // (4,512)
  float* out = (float*)d_out;                     // (256, 512, 64) as [op][b][h]
  char* ws = (char*)d_ws;

  k_prep<<<9, 256, 0, stream>>>(qkv_w, bn_qkv, relative, bn_sim, bn_out, ws);
  k_qkv<<<512, 512, 0, stream>>>(x, ws);
  k_attn<<<2048, 256, 0, stream>>>(ws, out);
}

// Round 20
// 84.277 us; speedup vs baseline: 1.0390x; 1.0390x over previous
//
#include <hip/hip_runtime.h>

#define EPS 1e-5f

typedef _Float16 half4_t __attribute__((ext_vector_type(4)));
typedef _Float16 half8_t __attribute__((ext_vector_type(8)));
typedef float floatx4 __attribute__((ext_vector_type(4)));

__device__ __forceinline__ unsigned short f2hb(float f) {
  _Float16 h = (_Float16)f;
  return __builtin_bit_cast(unsigned short, h);
}
__device__ __forceinline__ float hb2f(unsigned short u) {
  return (float)__builtin_bit_cast(_Float16, u);
}
__device__ __forceinline__ unsigned int pack2(float a, float b) {
  return (unsigned int)f2hb(a) | ((unsigned int)f2hb(b) << 16);
}

// ws layout (bytes):
//   qkv_h (fp16 v rows): [512 b][8 g][32 c][64 h]   @ 0         (16,777,216)
//   qkT   (fp16): [512 b][8 g][64 h][32 c]          @ 16777216  (16,777,216)
//   Wh    (fp16): [512 o][256 k]                    @ 33554432  (262,144)
//   relTq (fp16): [128 t][16 c]                     @ 33816576  (4096)
//   relTk (fp16): [128 t][16 c]                     @ 33820672  (4096)
//   relV  (fp16): [32 c][128 t]                     @ 33824768  (8192)
//   bnsF  (f32) : [8 g][4]                          @ 33832960  (128)
//   bnoSc (f32) : [512]                             @ 33833088  (2048)
//   bnoSh (f32) : [512]                             @ 33835136  (2048)
//   bnqSc (f32) : [512]                             @ 33837184  (2048)
//   bnqSh (f32) : [512]                             @ 33839232  (2048)
#define WS_QKT 16777216
#define WS_WH 33554432
#define WS_RELTQ 33816576
#define WS_RELTK 33820672
#define WS_RELV 33824768
#define WS_BNSF 33832960
#define WS_BNOSC 33833088
#define WS_BNOSH 33835136
#define WS_BNQSC 33837184
#define WS_BNQSH 33839232

// ---------------------------------------------------------------------------
// Kernel 0: prep. blocks 0..7: W -> Wh fp16. block 8: rel tables + folded BN.
// ---------------------------------------------------------------------------
__global__ __launch_bounds__(256) void k_prep(const float* __restrict__ W,
                                              const float* __restrict__ bnq,
                                              const float* __restrict__ rel,
                                              const float* __restrict__ bns,
                                              const float* __restrict__ bno,
                                              char* __restrict__ ws) {
  const int bid = blockIdx.x, tid = threadIdx.x;
  if (bid < 8) {
    unsigned short* Wh = (unsigned short*)(ws + WS_WH);
    const int base = bid * 16384;
#pragma unroll
    for (int u = 0; u < 16; ++u) {
      const int i = base + u * 1024 + tid * 4;
      const float4 v = *reinterpret_cast<const float4*>(&W[i]);
      uint2 p;
      p.x = pack2(v.x, v.y);
      p.y = pack2(v.z, v.w);
      *reinterpret_cast<uint2*>(&Wh[i]) = p;
    }
  } else {
    unsigned short* relTq = (unsigned short*)(ws + WS_RELTQ);
    unsigned short* relTk = (unsigned short*)(ws + WS_RELTK);
    unsigned short* relV = (unsigned short*)(ws + WS_RELV);
    float* bnsF = (float*)(ws + WS_BNSF);
    float* bnoSc = (float*)(ws + WS_BNOSC);
    float* bnoSh = (float*)(ws + WS_BNOSH);
    float* bnqSc = (float*)(ws + WS_BNQSC);
    float* bnqSh = (float*)(ws + WS_BNQSH);
    for (int idx = tid; idx < 2048; idx += 256) {
      const int t = idx >> 4, c = idx & 15;
      relTq[idx] = (t < 127) ? f2hb(rel[c * 127 + t]) : (unsigned short)0;
      relTk[idx] = (t < 127) ? f2hb(rel[(16 + c) * 127 + t]) : (unsigned short)0;
    }
    for (int idx = tid; idx < 4096; idx += 256) {
      const int c = idx >> 7, t = idx & 127;
      relV[idx] = (t < 127) ? f2hb(rel[(32 + c) * 127 + t]) : (unsigned short)0;
    }
    if (tid < 8) {
      const int g = tid;
      const float scA = bns[g] / sqrtf(bns[72 + g] + EPS);
      const float scB = bns[8 + g] / sqrtf(bns[72 + 8 + g] + EPS);
      const float scC = bns[16 + g] / sqrtf(bns[72 + 16 + g] + EPS);
      const float shv = (bns[24 + g] - bns[48 + g] * scA) +
                        (bns[24 + 8 + g] - bns[48 + 8 + g] * scB) +
                        (bns[24 + 16 + g] - bns[48 + 16 + g] * scC);
      bnsF[g * 4 + 0] = scA;
      bnsF[g * 4 + 1] = scB;
      bnsF[g * 4 + 2] = scC;
      bnsF[g * 4 + 3] = shv;
    }
    for (int idx = tid; idx < 512; idx += 256) {
      const float sc = bno[idx] / sqrtf(bno[1536 + idx] + EPS);
      bnoSc[idx] = sc;
      bnoSh[idx] = bno[512 + idx] - bno[1024 + idx] * sc;
      const float qc = bnq[idx] / sqrtf(bnq[1536 + idx] + EPS);
      bnqSc[idx] = qc;
      bnqSh[idx] = bnq[512 + idx] - bnq[1024 + idx] * qc;
    }
  }
}

// ---------------------------------------------------------------------------
// Kernel 1: fused qkv = BN(Wh @ x-slice). (unchanged from r16/r18)
// ---------------------------------------------------------------------------
__global__ __launch_bounds__(512, 4) void k_qkv(const float* __restrict__ x,
                                                char* __restrict__ ws) {
  const unsigned short* Wh = (const unsigned short*)(ws + WS_WH);
  const float* bnqSc = (const float*)(ws + WS_BNQSC);
  const float* bnqSh = (const float*)(ws + WS_BNQSH);
  unsigned short* qkv_h = (unsigned short*)ws;
  unsigned short* qkT = (unsigned short*)(ws + WS_QKT);
  __shared__ __align__(16) char arena[36864];
  unsigned short* xT = (unsigned short*)arena;    // [64 n][280]  35840B (ph A-B)
  unsigned short* qk_t = (unsigned short*)arena;  // [8 g][64 h][36] 36864B (ph C)

  const int tid = threadIdx.x;
  const int lane = tid & 63;
  const int w = tid >> 6;  // wave index == group g
  const int l15 = lane & 15, kg = lane >> 4;
  const size_t b = blockIdx.x;
  const int n0g = (int)b * 64;

  // ---- phase A: stage x slice -> xT fp16 [n][k], stride 280 ----
  {
    const int k = tid >> 1;         // 0..255
    const int nb = (tid & 1) * 32;  // 0 / 32
    const float* src = x + (size_t)k * 32768 + n0g + nb;
    unsigned short hv[32];
#pragma unroll
    for (int u = 0; u < 8; ++u) {
      const float4 v4 = *reinterpret_cast<const float4*>(src + u * 4);
      hv[u * 4 + 0] = f2hb(v4.x);
      hv[u * 4 + 1] = f2hb(v4.y);
      hv[u * 4 + 2] = f2hb(v4.z);
      hv[u * 4 + 3] = f2hb(v4.w);
    }
#pragma unroll
    for (int e = 0; e < 32; ++e) xT[(nb + e) * 280 + k] = hv[e];
  }
  __syncthreads();

  // ---- phase B: GEMM. wave w: o rows [w*64, w*64+64) x 64 n ----
  floatx4 acc[4][4] = {};
#pragma unroll
  for (int kk = 0; kk < 8; ++kk) {
    half8_t af[4], bf[4];
#pragma unroll
    for (int fm = 0; fm < 4; ++fm)
      af[fm] = *reinterpret_cast<const half8_t*>(Wh + (size_t)(w * 64 + fm * 16 + l15) * 256 +
                                                 kk * 32 + kg * 8);
#pragma unroll
    for (int fn = 0; fn < 4; ++fn)
      bf[fn] = *reinterpret_cast<const half8_t*>(xT + (fn * 16 + l15) * 280 + kk * 32 + kg * 8);
#pragma unroll
    for (int fm = 0; fm < 4; ++fm)
#pragma unroll
      for (int fn = 0; fn < 4; ++fn)
        acc[fm][fn] = __builtin_amdgcn_mfma_f32_16x16x32_f16(af[fm], bf[fn], acc[fm][fn], 0, 0, 0);
  }
  __syncthreads();  // xT dead; qk_t overlay live

  // ---- phase C: BN epilogue. q/k -> qk_t[h][c] (b64); v -> global direct ----
  const int o0 = w * 64;
#pragma unroll
  for (int fm = 0; fm < 4; ++fm) {
    const float4 sc4 = *reinterpret_cast<const float4*>(&bnqSc[o0 + fm * 16 + kg * 4]);
    const float4 sh4 = *reinterpret_cast<const float4*>(&bnqSh[o0 + fm * 16 + kg * 4]);
#pragma unroll
    for (int fn = 0; fn < 4; ++fn) {
      const int h = fn * 16 + l15;
      const float v0 = fmaf(acc[fm][fn][0], sc4.x, sh4.x);
      const float v1 = fmaf(acc[fm][fn][1], sc4.y, sh4.y);
      const float v2 = fmaf(acc[fm][fn][2], sc4.z, sh4.z);
      const float v3 = fmaf(acc[fm][fn][3], sc4.w, sh4.w);
      if (fm < 2) {
        uint2 p;
        p.x = pack2(v0, v1);
        p.y = pack2(v2, v3);
        *reinterpret_cast<uint2*>(&qk_t[w * 2304 + h * 36 + fm * 16 + kg * 4]) = p;
      } else {
        const int cb = (fm - 2) * 16 + kg * 4;
        unsigned short* dst = &qkv_h[((b * 8 + w) * 32 + cb) * 64 + h];
        dst[0] = f2hb(v0);
        dst[64] = f2hb(v1);
        dst[128] = f2hb(v2);
        dst[192] = f2hb(v3);
      }
    }
  }
  __syncthreads();
  // ---- cooperative coalesced qkT stores: 8 tiles x 4KB ----
#pragma unroll
  for (int it = 0; it < 4; ++it) {
    const int idx = it * 512 + tid;
    const int g2 = idx >> 8, e = idx & 255;
    const int h = e >> 2, c0 = (e & 3) * 8;
    const unsigned short* srcp = &qk_t[g2 * 2304 + h * 36 + c0];
    const uint2 a = *reinterpret_cast<const uint2*>(srcp);
    const uint2 b2 = *reinterpret_cast<const uint2*>(srcp + 4);
    uint4 wv;
    wv.x = a.x;
    wv.y = a.y;
    wv.z = b2.x;
    wv.w = b2.y;
    *reinterpret_cast<uint4*>(&qkT[((b * 8 + g2) * 64 + h) * 32 + c0]) = wv;
  }
}

// ---------------------------------------------------------------------------
// Kernel 2: per (b,g) attention, fp16 MFMA, in-register softmax.
//  BANDED SCATTER: M1/M2 MFMA outputs scattered directly into S-contribution
//  buffers Sb1[i][j]=scB*qr, Sb2[i][j]=scC*kr (bijective band maps, predicated
//  scalar stores, conflict-free). Phase 3a is stride-1 reads + adds — no
//  index math, no [128][64] M tables. Arena 31488 B -> 5 blocks/CU.
// ---------------------------------------------------------------------------
#define QKS 36   // qkL row stride (halves)
#define SBS 66   // Sb1/Sb2 row stride (halves)
#define PBS 72   // Pb / Vb row stride (halves)
#define PPS 136  // Pp row stride (halves)

__global__ __launch_bounds__(256, 4) void k_attn(const char* __restrict__ ws,
                                                 float* __restrict__ out) {
  const unsigned short* qkv_h = (const unsigned short*)ws;
  const unsigned short* qkTg = (const unsigned short*)(ws + WS_QKT);
  const unsigned short* relTq = (const unsigned short*)(ws + WS_RELTQ);
  const unsigned short* relTk = (const unsigned short*)(ws + WS_RELTK);
  const unsigned short* relV = (const unsigned short*)(ws + WS_RELV);
  const float* bnsF = (const float*)(ws + WS_BNSF);
  const float* bnoSc = (const float*)(ws + WS_BNOSC);
  const float* bnoSh = (const float*)(ws + WS_BNOSH);

  __shared__ __align__(16) char arena[31488];
  unsigned short* qkL = (unsigned short*)arena;            // [64][36]  4608  (ph1-2)
  unsigned short* Sb1 = (unsigned short*)(arena + 4608);   // [64][66]  8448  (ph2-3a)
  unsigned short* Sb2 = (unsigned short*)(arena + 13056);  // [64][66]  8448
  unsigned short* Pb = (unsigned short*)arena;             // [64][72]  9216  (ph3b-5)
  unsigned short* Pp = (unsigned short*)(arena + 9216);    // [64][136] 17408
  unsigned short* Vb = (unsigned short*)(arena + 26624);   // [32][72]  4608
  float* rowsumL = (float*)(arena + 31232);                // [64]       256

  const int tid = threadIdx.x;
  const int lane = tid & 63;
  const int wid = tid >> 6;
  const int l15 = lane & 15, kg = lane >> 4;
  const int bg = blockIdx.x;
  const int b = bg >> 3, g = bg & 7;
  const float4 bf = *reinterpret_cast<const float4*>(&bnsF[g * 4]);

  // ---- phase 1: stage qkT block (64x32 fp16, 4KB) ----
  {
    const uint4 qv =
        *reinterpret_cast<const uint4*>(&qkTg[(size_t)(((b << 3) + g)) * 2048 + tid * 8]);
    const int i = tid >> 2, c0 = (tid & 3) * 8;
    uint2 lo, hi;
    lo.x = qv.x;
    lo.y = qv.y;
    hi.x = qv.z;
    hi.y = qv.w;
    *reinterpret_cast<uint2*>(&qkL[i * QKS + c0]) = lo;
    *reinterpret_cast<uint2*>(&qkL[i * QKS + c0 + 4]) = hi;
  }
  __syncthreads();

  // ---- phase 2: K=16 MFMAs: qk (regs); M1/M2 band-scattered into Sb1/Sb2 ----
  floatx4 qkreg[4];
  {
    const half4_t aq = *reinterpret_cast<const half4_t*>(&qkL[(wid * 16 + l15) * QKS + kg * 4]);
    const half4_t ak =
        *reinterpret_cast<const half4_t*>(&qkL[(wid * 16 + l15) * QKS + 16 + kg * 4]);
    half4_t brq[8], brk[8];
#pragma unroll
    for (int nt = 0; nt < 8; ++nt) {
      brq[nt] = *reinterpret_cast<const half4_t*>(&relTq[(nt * 16 + l15) * 16 + kg * 4]);
      brk[nt] = *reinterpret_cast<const half4_t*>(&relTk[(nt * 16 + l15) * 16 + kg * 4]);
    }
    __builtin_amdgcn_s_setprio(1);
#pragma unroll
    for (int nt = 0; nt < 4; ++nt) {
      const half4_t bq =
          *reinterpret_cast<const half4_t*>(&qkL[(nt * 16 + l15) * QKS + 16 + kg * 4]);
      const floatx4 z = {};
      qkreg[nt] = __builtin_amdgcn_mfma_f32_16x16x16f16(aq, bq, z, 0, 0, 0);
    }
    const int mcol = wid * 16 + kg * 4;  // 4 consecutive A-rows
    // M1: D[t=nt*16+l15][i=mcol+reg]; j = i - t + 63; Sb1[i][j] = scB*val
#pragma unroll
    for (int nt = 0; nt < 8; ++nt) {
      const floatx4 z = {};
      const floatx4 cr = __builtin_amdgcn_mfma_f32_16x16x16f16(aq, brq[nt], z, 0, 0, 0);
      const int t = nt * 16 + l15;
#pragma unroll
      for (int reg = 0; reg < 4; ++reg) {
        const int i = mcol + reg;
        const int j = i - t + 63;
        if (j >= 0 && j < 64) Sb1[i * SBS + j] = f2hb(bf.y * cr[reg]);
      }
    }
    // M2: D[t=nt*16+l15][jj=mcol+reg]; i = jj - t + 63; Sb2[i][jj] = scC*val
#pragma unroll
    for (int nt = 0; nt < 8; ++nt) {
      const floatx4 z = {};
      const floatx4 cr = __builtin_amdgcn_mfma_f32_16x16x16f16(ak, brk[nt], z, 0, 0, 0);
      const int t = nt * 16 + l15;
#pragma unroll
      for (int reg = 0; reg < 4; ++reg) {
        const int jj = mcol + reg;
        const int i = jj - t + 63;
        if (i >= 0 && i < 64) Sb2[i * SBS + jj] = f2hb(bf.z * cr[reg]);
      }
    }
    __builtin_amdgcn_s_setprio(0);
  }
  __syncthreads();

  // ---- phase 3a: assemble S from qkreg + Sb1 + Sb2 (stride-1 reads) ----
  const uint4 vld = *reinterpret_cast<const uint4*>(
      &qkv_h[(((size_t)b * 8 + g) * 32 + (tid >> 3)) * 64 + (tid & 7) * 8]);
  float sreg[4][4];
#pragma unroll
  for (int nt = 0; nt < 4; ++nt) {
    const int j = nt * 16 + l15;
#pragma unroll
    for (int r = 0; r < 4; ++r) {
      const int i = wid * 16 + kg * 4 + r;
      const float qr = hb2f(Sb1[i * SBS + j]);
      const float kr = hb2f(Sb2[i * SBS + j]);
      sreg[nt][r] = fmaf(bf.x, qkreg[nt][r], qr + kr + bf.w);
    }
  }
  __syncthreads();  // Sb1/Sb2/qkL dead; Pb/Pp/Vb/rowsum overlay live

  // ---- phase 3b: in-register softmax; Pp zero (b64 segmented) + scatter ----
  float sm[4];
#pragma unroll
  for (int r = 0; r < 4; ++r) {
    float m = fmaxf(fmaxf(sreg[0][r], sreg[1][r]), fmaxf(sreg[2][r], sreg[3][r]));
    m = fmaxf(m, __shfl_xor(m, 1));
    m = fmaxf(m, __shfl_xor(m, 2));
    m = fmaxf(m, __shfl_xor(m, 4));
    m = fmaxf(m, __shfl_xor(m, 8));
    float s = 0.f;
#pragma unroll
    for (int nt = 0; nt < 4; ++nt) {
      sreg[nt][r] = __expf(sreg[nt][r] - m);
      s += sreg[nt][r];
    }
    s += __shfl_xor(s, 1);
    s += __shfl_xor(s, 2);
    s += __shfl_xor(s, 4);
    s += __shfl_xor(s, 8);
    sm[r] = s;
  }
#pragma unroll
  for (int r = 0; r < 4; ++r) {
    const int i = wid * 16 + kg * 4 + r;
    const int z0 = l15 * 4;
    if (z0 + 3 < i) {
      uint2 zz;
      zz.x = 0u;
      zz.y = 0u;
      *reinterpret_cast<uint2*>(&Pp[i * PPS + z0]) = zz;
    } else if (z0 >= i) {
      uint2 zz;
      zz.x = 0u;
      zz.y = 0u;
      *reinterpret_cast<uint2*>(&Pp[i * PPS + z0 + 64]) = zz;
    } else {
#pragma unroll
      for (int e = 0; e < 4; ++e) {
        const int z = z0 + e;
        Pp[i * PPS + (z < i ? z : z + 64)] = 0;
      }
    }
#pragma unroll
    for (int nt = 0; nt < 4; ++nt) {
      const int j = nt * 16 + l15;
      const unsigned short pv = f2hb(sreg[nt][r]);
      Pb[i * PBS + j] = pv;
      Pp[i * PPS + i + 63 - j] = pv;
    }
    if (l15 == 0) rowsumL[i] = sm[r];
  }
  {
    *reinterpret_cast<uint4*>(&Vb[(tid >> 3) * PBS + (tid & 7) * 8]) = vld;
  }
  __syncthreads();

  // ---- phase 5: swapped sv/sve MFMAs -> D[c][i]; direct global epilogue ----
  floatx4 sva[2] = {}, svea[2] = {};
  __builtin_amdgcn_s_setprio(1);
#pragma unroll
  for (int kk = 0; kk < 2; ++kk) {
    const half8_t pbf =
        *reinterpret_cast<const half8_t*>(&Pb[(wid * 16 + l15) * PBS + kk * 32 + kg * 8]);
#pragma unroll
    for (int cf = 0; cf < 2; ++cf) {
      const half8_t vb =
          *reinterpret_cast<const half8_t*>(&Vb[(cf * 16 + l15) * PBS + kk * 32 + kg * 8]);
      sva[cf] = __builtin_amdgcn_mfma_f32_16x16x32_f16(vb, pbf, sva[cf], 0, 0, 0);
    }
  }
#pragma unroll
  for (int kk = 0; kk < 4; ++kk) {
    const half8_t ppf =
        *reinterpret_cast<const half8_t*>(&Pp[(wid * 16 + l15) * PPS + kk * 32 + kg * 8]);
#pragma unroll
    for (int cf = 0; cf < 2; ++cf) {
      const half8_t rb =
          *reinterpret_cast<const half8_t*>(&relV[(cf * 16 + l15) * 128 + kk * 32 + kg * 8]);
      svea[cf] = __builtin_amdgcn_mfma_f32_16x16x32_f16(rb, ppf, svea[cf], 0, 0, 0);
    }
  }
  __builtin_amdgcn_s_setprio(0);
  {
    const int i = wid * 16 + l15;
    const float inv = 1.0f / rowsumL[i];
#pragma unroll
    for (int cf = 0; cf < 2; ++cf) {
#pragma unroll
      for (int reg = 0; reg < 4; ++reg) {
        const int c = cf * 16 + kg * 4 + reg;
        const int ch = ((g << 5) + c) * 2;
        const float2 scv = *reinterpret_cast<const float2*>(&bnoSc[ch]);
        const float2 shv = *reinterpret_cast<const float2*>(&bnoSh[ch]);
        out[(size_t)((g << 5) + c) * 32768 + (size_t)b * 64 + i] =
            fmaf(scv.x, sva[cf][reg] * inv, shv.x) + fmaf(scv.y, svea[cf][reg] * inv, shv.y);
      }
    }
  }
}

extern "C" void kernel_launch(void* const* d_in, const int* in_sizes, int n_in,
                              void* d_out, int out_size, void* d_ws, size_t ws_size,
                              hipStream_t stream) {
  const float* x = (const float*)d_in[0];         // (1,256,16,32,64)
  const float* qkv_w = (const float*)d_in[1];     // (512,256)
  const float* relative = (const float*)d_in[2];  // (64,127)
  const float* bn_qkv = (const float*)d_in[3];    // (4,512)
  const float* bn_sim = (const float*)d_in[4];    // (4,24)
  const float* bn_out = (const float*)d_in[5];    // (4,512)
  float* out = (float*)d_out;                     // (256, 512, 64) as [op][b][h]
  char* ws = (char*)d_ws;

  k_prep<<<9, 256, 0, stream>>>(qkv_w, bn_qkv, relative, bn_sim, bn_out, ws);
  k_qkv<<<512, 512, 0, stream>>>(x, ws);
  k_attn<<<4096, 256, 0, stream>>>(ws, out);
}

// Round 22
// 77.933 us; speedup vs baseline: 1.1235x; 1.0814x over previous
//
#include <hip/hip_runtime.h>

#define EPS 1e-5f

typedef _Float16 half4_t __attribute__((ext_vector_type(4)));
typedef _Float16 half8_t __attribute__((ext_vector_type(8)));
typedef float floatx4 __attribute__((ext_vector_type(4)));

__device__ __forceinline__ unsigned short f2hb(float f) {
  _Float16 h = (_Float16)f;
  return __builtin_bit_cast(unsigned short, h);
}
__device__ __forceinline__ float hb2f(unsigned short u) {
  return (float)__builtin_bit_cast(_Float16, u);
}
__device__ __forceinline__ unsigned int pack2(float a, float b) {
  return (unsigned int)f2hb(a) | ((unsigned int)f2hb(b) << 16);
}

// ws layout (bytes):
//   qkv_h (fp16 v rows): [512 b][8 g][32 c][64 h]   @ 0         (16,777,216)
//   qkT   (fp16): [512 b][8 g][64 h][32 c]          @ 16777216  (16,777,216)
//   Wh    (fp16): [512 o][256 k]                    @ 33554432  (262,144)
//   relTq (fp16): [128 t][16 c]                     @ 33816576  (4096)
//   relTk (fp16): [128 t][16 c]                     @ 33820672  (4096)
//   relV  (fp16): [32 c][128 t]                     @ 33824768  (8192)
//   bnsF  (f32) : [8 g][4]                          @ 33832960  (128)
//   bnoSc (f32) : [512]                             @ 33833088  (2048)
//   bnoSh (f32) : [512]                             @ 33835136  (2048)
//   bnqSc (f32) : [512]                             @ 33837184  (2048)
//   bnqSh (f32) : [512]                             @ 33839232  (2048)
#define WS_QKT 16777216
#define WS_WH 33554432
#define WS_RELTQ 33816576
#define WS_RELTK 33820672
#define WS_RELV 33824768
#define WS_BNSF 33832960
#define WS_BNOSC 33833088
#define WS_BNOSH 33835136
#define WS_BNQSC 33837184
#define WS_BNQSH 33839232

// ---------------------------------------------------------------------------
// Kernel 0: prep. blocks 0..7: W -> Wh fp16. block 8: rel tables + folded BN.
// ---------------------------------------------------------------------------
__global__ __launch_bounds__(256) void k_prep(const float* __restrict__ W,
                                              const float* __restrict__ bnq,
                                              const float* __restrict__ rel,
                                              const float* __restrict__ bns,
                                              const float* __restrict__ bno,
                                              char* __restrict__ ws) {
  const int bid = blockIdx.x, tid = threadIdx.x;
  if (bid < 8) {
    unsigned short* Wh = (unsigned short*)(ws + WS_WH);
    const int base = bid * 16384;
#pragma unroll
    for (int u = 0; u < 16; ++u) {
      const int i = base + u * 1024 + tid * 4;
      const float4 v = *reinterpret_cast<const float4*>(&W[i]);
      uint2 p;
      p.x = pack2(v.x, v.y);
      p.y = pack2(v.z, v.w);
      *reinterpret_cast<uint2*>(&Wh[i]) = p;
    }
  } else {
    unsigned short* relTq = (unsigned short*)(ws + WS_RELTQ);
    unsigned short* relTk = (unsigned short*)(ws + WS_RELTK);
    unsigned short* relV = (unsigned short*)(ws + WS_RELV);
    float* bnsF = (float*)(ws + WS_BNSF);
    float* bnoSc = (float*)(ws + WS_BNOSC);
    float* bnoSh = (float*)(ws + WS_BNOSH);
    float* bnqSc = (float*)(ws + WS_BNQSC);
    float* bnqSh = (float*)(ws + WS_BNQSH);
    for (int idx = tid; idx < 2048; idx += 256) {
      const int t = idx >> 4, c = idx & 15;
      relTq[idx] = (t < 127) ? f2hb(rel[c * 127 + t]) : (unsigned short)0;
      relTk[idx] = (t < 127) ? f2hb(rel[(16 + c) * 127 + t]) : (unsigned short)0;
    }
    for (int idx = tid; idx < 4096; idx += 256) {
      const int c = idx >> 7, t = idx & 127;
      relV[idx] = (t < 127) ? f2hb(rel[(32 + c) * 127 + t]) : (unsigned short)0;
    }
    if (tid < 8) {
      const int g = tid;
      const float scA = bns[g] / sqrtf(bns[72 + g] + EPS);
      const float scB = bns[8 + g] / sqrtf(bns[72 + 8 + g] + EPS);
      const float scC = bns[16 + g] / sqrtf(bns[72 + 16 + g] + EPS);
      const float shv = (bns[24 + g] - bns[48 + g] * scA) +
                        (bns[24 + 8 + g] - bns[48 + 8 + g] * scB) +
                        (bns[24 + 16 + g] - bns[48 + 16 + g] * scC);
      bnsF[g * 4 + 0] = scA;
      bnsF[g * 4 + 1] = scB;
      bnsF[g * 4 + 2] = scC;
      bnsF[g * 4 + 3] = shv;
    }
    for (int idx = tid; idx < 512; idx += 256) {
      const float sc = bno[idx] / sqrtf(bno[1536 + idx] + EPS);
      bnoSc[idx] = sc;
      bnoSh[idx] = bno[512 + idx] - bno[1024 + idx] * sc;
      const float qc = bnq[idx] / sqrtf(bnq[1536 + idx] + EPS);
      bnqSc[idx] = qc;
      bnqSh[idx] = bnq[512 + idx] - bnq[1024 + idx] * qc;
    }
  }
}

// ---------------------------------------------------------------------------
// Kernel 1: fused qkv = BN(Wh @ x-slice). (unchanged from r16/r18)
// ---------------------------------------------------------------------------
__global__ __launch_bounds__(512, 4) void k_qkv(const float* __restrict__ x,
                                                char* __restrict__ ws) {
  const unsigned short* Wh = (const unsigned short*)(ws + WS_WH);
  const float* bnqSc = (const float*)(ws + WS_BNQSC);
  const float* bnqSh = (const float*)(ws + WS_BNQSH);
  unsigned short* qkv_h = (unsigned short*)ws;
  unsigned short* qkT = (unsigned short*)(ws + WS_QKT);
  __shared__ __align__(16) char arena[36864];
  unsigned short* xT = (unsigned short*)arena;    // [64 n][280]  35840B (ph A-B)
  unsigned short* qk_t = (unsigned short*)arena;  // [8 g][64 h][36] 36864B (ph C)

  const int tid = threadIdx.x;
  const int lane = tid & 63;
  const int w = tid >> 6;  // wave index == group g
  const int l15 = lane & 15, kg = lane >> 4;
  const size_t b = blockIdx.x;
  const int n0g = (int)b * 64;

  // ---- phase A: stage x slice -> xT fp16 [n][k], stride 280 ----
  {
    const int k = tid >> 1;         // 0..255
    const int nb = (tid & 1) * 32;  // 0 / 32
    const float* src = x + (size_t)k * 32768 + n0g + nb;
    unsigned short hv[32];
#pragma unroll
    for (int u = 0; u < 8; ++u) {
      const float4 v4 = *reinterpret_cast<const float4*>(src + u * 4);
      hv[u * 4 + 0] = f2hb(v4.x);
      hv[u * 4 + 1] = f2hb(v4.y);
      hv[u * 4 + 2] = f2hb(v4.z);
      hv[u * 4 + 3] = f2hb(v4.w);
    }
#pragma unroll
    for (int e = 0; e < 32; ++e) xT[(nb + e) * 280 + k] = hv[e];
  }
  __syncthreads();

  // ---- phase B: GEMM. wave w: o rows [w*64, w*64+64) x 64 n ----
  floatx4 acc[4][4] = {};
#pragma unroll
  for (int kk = 0; kk < 8; ++kk) {
    half8_t af[4], bf[4];
#pragma unroll
    for (int fm = 0; fm < 4; ++fm)
      af[fm] = *reinterpret_cast<const half8_t*>(Wh + (size_t)(w * 64 + fm * 16 + l15) * 256 +
                                                 kk * 32 + kg * 8);
#pragma unroll
    for (int fn = 0; fn < 4; ++fn)
      bf[fn] = *reinterpret_cast<const half8_t*>(xT + (fn * 16 + l15) * 280 + kk * 32 + kg * 8);
#pragma unroll
    for (int fm = 0; fm < 4; ++fm)
#pragma unroll
      for (int fn = 0; fn < 4; ++fn)
        acc[fm][fn] = __builtin_amdgcn_mfma_f32_16x16x32_f16(af[fm], bf[fn], acc[fm][fn], 0, 0, 0);
  }
  __syncthreads();  // xT dead; qk_t overlay live

  // ---- phase C: BN epilogue. q/k -> qk_t[h][c] (b64); v -> global direct ----
  const int o0 = w * 64;
#pragma unroll
  for (int fm = 0; fm < 4; ++fm) {
    const float4 sc4 = *reinterpret_cast<const float4*>(&bnqSc[o0 + fm * 16 + kg * 4]);
    const float4 sh4 = *reinterpret_cast<const float4*>(&bnqSh[o0 + fm * 16 + kg * 4]);
#pragma unroll
    for (int fn = 0; fn < 4; ++fn) {
      const int h = fn * 16 + l15;
      const float v0 = fmaf(acc[fm][fn][0], sc4.x, sh4.x);
      const float v1 = fmaf(acc[fm][fn][1], sc4.y, sh4.y);
      const float v2 = fmaf(acc[fm][fn][2], sc4.z, sh4.z);
      const float v3 = fmaf(acc[fm][fn][3], sc4.w, sh4.w);
      if (fm < 2) {
        uint2 p;
        p.x = pack2(v0, v1);
        p.y = pack2(v2, v3);
        *reinterpret_cast<uint2*>(&qk_t[w * 2304 + h * 36 + fm * 16 + kg * 4]) = p;
      } else {
        const int cb = (fm - 2) * 16 + kg * 4;
        unsigned short* dst = &qkv_h[((b * 8 + w) * 32 + cb) * 64 + h];
        dst[0] = f2hb(v0);
        dst[64] = f2hb(v1);
        dst[128] = f2hb(v2);
        dst[192] = f2hb(v3);
      }
    }
  }
  __syncthreads();
  // ---- cooperative coalesced qkT stores: 8 tiles x 4KB ----
#pragma unroll
  for (int it = 0; it < 4; ++it) {
    const int idx = it * 512 + tid;
    const int g2 = idx >> 8, e = idx & 255;
    const int h = e >> 2, c0 = (e & 3) * 8;
    const unsigned short* srcp = &qk_t[g2 * 2304 + h * 36 + c0];
    const uint2 a = *reinterpret_cast<const uint2*>(srcp);
    const uint2 b2 = *reinterpret_cast<const uint2*>(srcp + 4);
    uint4 wv;
    wv.x = a.x;
    wv.y = a.y;
    wv.z = b2.x;
    wv.w = b2.y;
    *reinterpret_cast<uint4*>(&qkT[((b * 8 + g2) * 64 + h) * 32 + c0]) = wv;
  }
}

// ---------------------------------------------------------------------------
// Kernel 2: per (b,g) attention (r18 structure), 127-row M tables (arena
// 32512 B -> targets 5 blocks/CU). Windowed K=96 sve with CLAMPED window
// t0 = min(wid*16, 32) so [t0, t0+96) stays inside [0,128) and covers the
// band [i, i+63] for all i in the tile (r21 bug: wid=3 window overran row).
// ---------------------------------------------------------------------------
#define QKS 36   // qkL row stride (halves)
#define PBS 72   // Pb / Vb row stride (halves)
#define PPS 136  // Pp row stride (halves)

__global__ __launch_bounds__(256, 4) void k_attn(const char* __restrict__ ws,
                                                 float* __restrict__ out) {
  const unsigned short* qkv_h = (const unsigned short*)ws;
  const unsigned short* qkTg = (const unsigned short*)(ws + WS_QKT);
  const unsigned short* relTq = (const unsigned short*)(ws + WS_RELTQ);
  const unsigned short* relTk = (const unsigned short*)(ws + WS_RELTK);
  const unsigned short* relV = (const unsigned short*)(ws + WS_RELV);
  const float* bnsF = (const float*)(ws + WS_BNSF);
  const float* bnoSc = (const float*)(ws + WS_BNOSC);
  const float* bnoSh = (const float*)(ws + WS_BNOSH);

  __shared__ __align__(16) char arena[32512];
  unsigned short* qkL = (unsigned short*)arena;            // [64][36]   4608 (ph1, overlaid)
  unsigned short* M1T = (unsigned short*)arena;            // [127][64] 16256 (ph2-3a)
  unsigned short* M2T = (unsigned short*)(arena + 16256);  // [127][64] 16256
  unsigned short* Pb = (unsigned short*)arena;             // [64][72]   9216 (ph3b-5)
  unsigned short* Pp = (unsigned short*)(arena + 9216);    // [64][136] 17408
  unsigned short* Vb = (unsigned short*)(arena + 26624);   // [32][72]   4608
  float* rowsumL = (float*)(arena + 31232);                // [64]        256

  const int tid = threadIdx.x;
  const int lane = tid & 63;
  const int wid = tid >> 6;
  const int l15 = lane & 15, kg = lane >> 4;
  const int bg = blockIdx.x;
  const int b = bg >> 3, g = bg & 7;

  // ---- phase 1: stage qkT block (64x32 fp16, 4KB) ----
  {
    const uint4 qv =
        *reinterpret_cast<const uint4*>(&qkTg[(size_t)(((b << 3) + g)) * 2048 + tid * 8]);
    const int i = tid >> 2, c0 = (tid & 3) * 8;
    uint2 lo, hi;
    lo.x = qv.x;
    lo.y = qv.y;
    hi.x = qv.z;
    hi.y = qv.w;
    *reinterpret_cast<uint2*>(&qkL[i * QKS + c0]) = lo;
    *reinterpret_cast<uint2*>(&qkL[i * QKS + c0 + 4]) = hi;
  }
  __syncthreads();

  // ---- phase 1b: preload q/k fragments to registers (qkL dies after) ----
  const half4_t aq = *reinterpret_cast<const half4_t*>(&qkL[(wid * 16 + l15) * QKS + kg * 4]);
  const half4_t ak =
      *reinterpret_cast<const half4_t*>(&qkL[(wid * 16 + l15) * QKS + 16 + kg * 4]);
  half4_t bqr[4];
#pragma unroll
  for (int nt = 0; nt < 4; ++nt)
    bqr[nt] = *reinterpret_cast<const half4_t*>(&qkL[(nt * 16 + l15) * QKS + 16 + kg * 4]);
  __syncthreads();  // qkL dead; M1T/M2T overlay live

  // ---- phase 2: K=16 MFMAs: qk (regs), M1T/M2T (swizzled stride-64) ----
  floatx4 qkreg[4];
  {
    half4_t brq[8], brk[8];
#pragma unroll
    for (int nt = 0; nt < 8; ++nt) {
      brq[nt] = *reinterpret_cast<const half4_t*>(&relTq[(nt * 16 + l15) * 16 + kg * 4]);
      brk[nt] = *reinterpret_cast<const half4_t*>(&relTk[(nt * 16 + l15) * 16 + kg * 4]);
    }
    __builtin_amdgcn_s_setprio(1);
#pragma unroll
    for (int nt = 0; nt < 4; ++nt) {
      const floatx4 z = {};
      qkreg[nt] = __builtin_amdgcn_mfma_f32_16x16x16f16(aq, bqr[nt], z, 0, 0, 0);
    }
    const int mcol = wid * 16 + kg * 4;  // 4 consecutive i (or j)
#pragma unroll
    for (int nt = 0; nt < 8; ++nt) {
      const floatx4 z = {};
      const floatx4 cr = __builtin_amdgcn_mfma_f32_16x16x16f16(aq, brq[nt], z, 0, 0, 0);
      const int row = nt * 16 + l15;
      if (row < 127) {
        uint2 p;
        p.x = pack2(cr[0], cr[1]);
        p.y = pack2(cr[2], cr[3]);
        *reinterpret_cast<uint2*>(&M1T[row * 64 + (mcol ^ ((row & 7) << 3))]) = p;
      }
    }
#pragma unroll
    for (int nt = 0; nt < 8; ++nt) {
      const floatx4 z = {};
      const floatx4 cr = __builtin_amdgcn_mfma_f32_16x16x16f16(ak, brk[nt], z, 0, 0, 0);
      const int row = nt * 16 + l15;
      if (row < 127) {
        uint2 p;
        p.x = pack2(cr[0], cr[1]);
        p.y = pack2(cr[2], cr[3]);
        *reinterpret_cast<uint2*>(&M2T[row * 64 + (mcol ^ ((row & 7) << 3))]) = p;
      }
    }
    __builtin_amdgcn_s_setprio(0);
  }
  __syncthreads();

  // ---- phase 3a: gather M1T/M2T (swizzled), assemble S; prefetch V ----
  const uint4 vld = *reinterpret_cast<const uint4*>(
      &qkv_h[(((size_t)b * 8 + g) * 32 + (tid >> 3)) * 64 + (tid & 7) * 8]);
  float sreg[4][4];
  {
    const float4 bf = *reinterpret_cast<const float4*>(&bnsF[g * 4]);
#pragma unroll
    for (int nt = 0; nt < 4; ++nt) {
      const int j = nt * 16 + l15;
#pragma unroll
      for (int r = 0; r < 4; ++r) {
        const int i = wid * 16 + kg * 4 + r;
        const int d = i - j + 63;  // 0..126
        const int d2 = 126 - d;
        const float qr = hb2f(M1T[d * 64 + (i ^ ((d & 7) << 3))]);
        const float kr = hb2f(M2T[d2 * 64 + (j ^ ((d2 & 7) << 3))]);
        sreg[nt][r] = fmaf(bf.x, qkreg[nt][r], fmaf(bf.y, qr, fmaf(bf.z, kr, bf.w)));
      }
    }
  }
  __syncthreads();  // M1T/M2T dead; Pb/Pp/Vb/rowsum overlay live

  // ---- phase 3b: in-register softmax; Pp zero (b64 segmented) + scatter ----
  float sm[4];
#pragma unroll
  for (int r = 0; r < 4; ++r) {
    float m = fmaxf(fmaxf(sreg[0][r], sreg[1][r]), fmaxf(sreg[2][r], sreg[3][r]));
    m = fmaxf(m, __shfl_xor(m, 1));
    m = fmaxf(m, __shfl_xor(m, 2));
    m = fmaxf(m, __shfl_xor(m, 4));
    m = fmaxf(m, __shfl_xor(m, 8));
    float s = 0.f;
#pragma unroll
    for (int nt = 0; nt < 4; ++nt) {
      sreg[nt][r] = __expf(sreg[nt][r] - m);
      s += sreg[nt][r];
    }
    s += __shfl_xor(s, 1);
    s += __shfl_xor(s, 2);
    s += __shfl_xor(s, 4);
    s += __shfl_xor(s, 8);
    sm[r] = s;
  }
#pragma unroll
  for (int r = 0; r < 4; ++r) {
    const int i = wid * 16 + kg * 4 + r;
    const int z0 = l15 * 4;
    if (z0 + 3 < i) {
      uint2 zz;
      zz.x = 0u;
      zz.y = 0u;
      *reinterpret_cast<uint2*>(&Pp[i * PPS + z0]) = zz;
    } else if (z0 >= i) {
      uint2 zz;
      zz.x = 0u;
      zz.y = 0u;
      *reinterpret_cast<uint2*>(&Pp[i * PPS + z0 + 64]) = zz;
    } else {
#pragma unroll
      for (int e = 0; e < 4; ++e) {
        const int z = z0 + e;
        Pp[i * PPS + (z < i ? z : z + 64)] = 0;
      }
    }
#pragma unroll
    for (int nt = 0; nt < 4; ++nt) {
      const int j = nt * 16 + l15;
      const unsigned short pv = f2hb(sreg[nt][r]);
      Pb[i * PBS + j] = pv;
      Pp[i * PPS + i + 63 - j] = pv;
    }
    if (l15 == 0) rowsumL[i] = sm[r];
  }
  {
    *reinterpret_cast<uint4*>(&Vb[(tid >> 3) * PBS + (tid & 7) * 8]) = vld;
  }
  __syncthreads();

  // ---- phase 5: swapped sv/sve MFMAs -> D[c][i]; clamped K=96 sve window ----
  floatx4 sva[2] = {}, svea[2] = {};
  __builtin_amdgcn_s_setprio(1);
#pragma unroll
  for (int kk = 0; kk < 2; ++kk) {
    const half8_t pbf =
        *reinterpret_cast<const half8_t*>(&Pb[(wid * 16 + l15) * PBS + kk * 32 + kg * 8]);
#pragma unroll
    for (int cf = 0; cf < 2; ++cf) {
      const half8_t vb =
          *reinterpret_cast<const half8_t*>(&Vb[(cf * 16 + l15) * PBS + kk * 32 + kg * 8]);
      sva[cf] = __builtin_amdgcn_mfma_f32_16x16x32_f16(vb, pbf, sva[cf], 0, 0, 0);
    }
  }
  {
    const int t0 = (wid < 3) ? wid * 16 : 32;  // clamped: window stays in [0,128)
#pragma unroll
    for (int kk = 0; kk < 3; ++kk) {
      const half8_t ppf = *reinterpret_cast<const half8_t*>(
          &Pp[(wid * 16 + l15) * PPS + t0 + kk * 32 + kg * 8]);
#pragma unroll
      for (int cf = 0; cf < 2; ++cf) {
        const half8_t rb = *reinterpret_cast<const half8_t*>(
            &relV[(cf * 16 + l15) * 128 + t0 + kk * 32 + kg * 8]);
        svea[cf] = __builtin_amdgcn_mfma_f32_16x16x32_f16(rb, ppf, svea[cf], 0, 0, 0);
      }
    }
  }
  __builtin_amdgcn_s_setprio(0);
  {
    const int i = wid * 16 + l15;
    const float inv = 1.0f / rowsumL[i];
#pragma unroll
    for (int cf = 0; cf < 2; ++cf) {
#pragma unroll
      for (int reg = 0; reg < 4; ++reg) {
        const int c = cf * 16 + kg * 4 + reg;
        const int ch = ((g << 5) + c) * 2;
        const float2 scv = *reinterpret_cast<const float2*>(&bnoSc[ch]);
        const float2 shv = *reinterpret_cast<const float2*>(&bnoSh[ch]);
        out[(size_t)((g << 5) + c) * 32768 + (size_t)b * 64 + i] =
            fmaf(scv.x, sva[cf][reg] * inv, shv.x) + fmaf(scv.y, svea[cf][reg] * inv, shv.y);
      }
    }
  }
}

extern "C" void kernel_launch(void* const* d_in, const int* in_sizes, int n_in,
                              void* d_out, int out_size, void* d_ws, size_t ws_size,
                              hipStream_t stream) {
  const float* x = (const float*)d_in[0];         // (1,256,16,32,64)
  const float* qkv_w = (const float*)d_in[1];     // (512,256)
  const float* relative = (const float*)d_in[2];  // (64,127)
  const float* bn_qkv = (const float*)d_in[3];    // (4,512)
  const float* bn_sim = (const float*)d_in[4];    // (4,24)
  const float* bn_out = (const float*)d_in[5];    // (4,512)
  float* out = (float*)d_out;                     // (256, 512, 64) as [op][b][h]
  char* ws = (char*)d_ws;

  k_prep<<<9, 256, 0, stream>>>(qkv_w, bn_qkv, relative, bn_sim, bn_out, ws);
  k_qkv<<<512, 512, 0, stream>>>(x, ws);
  k_attn<<<4096, 256, 0, stream>>>(ws, out);
}